// Round 3
// baseline (230.965 us; speedup 1.0000x reference)
//
#include <hip/hip_runtime.h>

typedef unsigned short u16;
typedef unsigned int u32;
typedef __bf16 bf16x8 __attribute__((ext_vector_type(8)));
typedef float f32x4 __attribute__((ext_vector_type(4)));
typedef u16 u16x8 __attribute__((ext_vector_type(8)));
typedef u16 u16x4 __attribute__((ext_vector_type(4)));

#define NH 16
#define DKK 64
#define SQ 2048
#define DD 1024

__device__ inline u16 f2bf(float f) {
  union { float f; u32 u; } v; v.f = f;
  u32 u = v.u;
  u += 0x7FFFu + ((u >> 16) & 1u);
  return (u16)(u >> 16);
}

__device__ inline u16x8 cvt8(const float* p) {
  float4 a = *(const float4*)p;
  float4 b = *(const float4*)(p + 4);
  u16x8 v;
  v[0] = f2bf(a.x); v[1] = f2bf(a.y); v[2] = f2bf(a.z); v[3] = f2bf(a.w);
  v[4] = f2bf(b.x); v[5] = f2bf(b.y); v[6] = f2bf(b.z); v[7] = f2bf(b.w);
  return v;
}

// ---------------- Weight transpose: W(H,D,dk) f32 x3 -> WT bf16 [(t*1024 + h*64 + kk)][d] ----------------
__global__ __launch_bounds__(256) void wt_kernel(const float* __restrict__ Wq,
                                                 const float* __restrict__ Wk,
                                                 const float* __restrict__ Wv,
                                                 u16* __restrict__ WT) {
  __shared__ u16 sm[64][72];
  int bid = blockIdx.x;
  int t = bid >> 8;                // tensor 0..2
  int rem = bid & 255;
  int h = rem >> 4;                // head
  int d0 = (rem & 15) * 64;        // d tile
  const float* src = (t == 0) ? Wq : (t == 1) ? Wk : Wv;
  int tid = threadIdx.x;
  for (int j = 0; j < 2; ++j) {
    int idx = tid + j * 256;
    int r = idx >> 3;              // d offset 0..63
    int c0 = (idx & 7) * 8;        // kk 0..63 step 8
    *(u16x8*)&sm[r][c0] = cvt8(&src[(h * DD + d0 + r) * DKK + c0]);
  }
  __syncthreads();
  for (int j = 0; j < 2; ++j) {
    int idx = tid + j * 256;
    int r2 = idx >> 3;             // kk 0..63
    int c0 = (idx & 7) * 8;        // d offset
    u16x8 vv;
    for (int i = 0; i < 8; ++i) vv[i] = sm[c0 + i][r2];
    int n = t * 1024 + h * 64 + r2;
    *(u16x8*)&WT[n * DD + d0 + c0] = vv;
  }
}

// ---------------- QKV GEMM: A=x f32 [M,K]; B=WT bf16 [N,K]; 64x64 tile, 4 waves, BK=32 ----------------
__global__ __launch_bounds__(256) void gemm_qkv(const float* __restrict__ A,
                                                const u16* __restrict__ Bm,
                                                u16* __restrict__ o0,
                                                u16* __restrict__ o1,
                                                u16* __restrict__ o2) {
  __shared__ u16 As[64][40];
  __shared__ u16 Bs[64][40];
  const int K = 1024;
  int m0 = blockIdx.x * 64;
  int n0 = blockIdx.y * 64;
  int tid = threadIdx.x;
  int w = tid >> 6, l = tid & 63;
  int lg = l >> 4, lr = l & 15;
  f32x4 acc[4] = {};
  int r = tid >> 2;             // 0..63
  int c0 = (tid & 3) * 8;       // 0..31
  for (int kt = 0; kt < K / 32; ++kt) {
    int k0 = kt * 32;
    *(u16x8*)&As[r][c0] = cvt8(&A[(size_t)(m0 + r) * K + k0 + c0]);
    *(u16x8*)&Bs[r][c0] = *(const u16x8*)&Bm[(n0 + r) * K + k0 + c0];
    __syncthreads();
    bf16x8 a = *(const bf16x8*)&As[w * 16 + lr][lg * 8];
    for (int j = 0; j < 4; ++j) {
      bf16x8 b = *(const bf16x8*)&Bs[j * 16 + lr][lg * 8];
      acc[j] = __builtin_amdgcn_mfma_f32_16x16x32_bf16(a, b, acc[j], 0, 0, 0);
    }
    __syncthreads();
  }
  int mrow = m0 + w * 16 + lg * 4;
  int t = n0 >> 10;           // 0=Q 1=K 2=V
  int h = (n0 & 1023) >> 6;   // head (uniform: BN=64 aligned)
  int b = mrow >> 11;
  int s = mrow & 2047;
  for (int j = 0; j < 4; ++j) {
    int kk = j * 16 + lr;
    if (t < 2) {
      u16* o = (t == 0) ? o0 : o1;
      for (int rr = 0; rr < 4; ++rr)
        o[((size_t)(b * NH + h) * SQ + s + rr) * DKK + kk] = f2bf(acc[j][rr]);
    } else {
      u16x4 vv;
      for (int rr = 0; rr < 4; ++rr) vv[rr] = f2bf(acc[j][rr]);
      *(u16x4*)&o2[((size_t)(b * NH + h) * DKK + kk) * SQ + s] = vv;
    }
  }
}

// ---------------- Output GEMM: A=Cc bf16 [M,K]; B=Wo f32 [N,K]; store f32 ----------------
__global__ __launch_bounds__(256) void gemm_out(const u16* __restrict__ A,
                                                const float* __restrict__ Bm,
                                                float* __restrict__ out) {
  __shared__ u16 As[64][40];
  __shared__ u16 Bs[64][40];
  const int K = 1024;
  int m0 = blockIdx.x * 64;
  int n0 = blockIdx.y * 64;
  int tid = threadIdx.x;
  int w = tid >> 6, l = tid & 63;
  int lg = l >> 4, lr = l & 15;
  f32x4 acc[4] = {};
  int r = tid >> 2;
  int c0 = (tid & 3) * 8;
  for (int kt = 0; kt < K / 32; ++kt) {
    int k0 = kt * 32;
    *(u16x8*)&As[r][c0] = *(const u16x8*)&A[(size_t)(m0 + r) * K + k0 + c0];
    *(u16x8*)&Bs[r][c0] = cvt8(&Bm[(size_t)(n0 + r) * K + k0 + c0]);
    __syncthreads();
    bf16x8 a = *(const bf16x8*)&As[w * 16 + lr][lg * 8];
    for (int j = 0; j < 4; ++j) {
      bf16x8 b = *(const bf16x8*)&Bs[j * 16 + lr][lg * 8];
      acc[j] = __builtin_amdgcn_mfma_f32_16x16x32_bf16(a, b, acc[j], 0, 0, 0);
    }
    __syncthreads();
  }
  int mrow = m0 + w * 16 + lg * 4;
  for (int j = 0; j < 4; ++j) {
    int n = n0 + j * 16 + lr;
    for (int rr = 0; rr < 4; ++rr)
      out[(size_t)(mrow + rr) * 1024 + n] = acc[j][rr];
  }
}

// ---------------- Flash attention: 64 q-rows/block, 4 waves x 16 rows, kv tiles of 64 ----------------
__global__ __launch_bounds__(256) void attn_kernel(const u16* __restrict__ Q,
                                                   const u16* __restrict__ Kg,
                                                   const u16* __restrict__ Vt,
                                                   u16* __restrict__ Cc) {
  __shared__ u16 Qs[64][72];
  __shared__ u16 Ks[64][72];
  __shared__ u16 Vs[64][72];   // Vs[dk][kv]
  __shared__ u16 Ps[4][16][72];
  int qt = blockIdx.x;
  int bh = blockIdx.y;
  int tid = threadIdx.x;
  int w = tid >> 6, l = tid & 63;
  int lg = l >> 4, lr = l & 15;
  const u16* Qp = Q + (size_t)bh * SQ * DKK;
  const u16* Kp = Kg + (size_t)bh * SQ * DKK;
  const u16* Vp = Vt + (size_t)bh * DKK * SQ;

  for (int j = 0; j < 2; ++j) {
    int idx = tid + j * 256;
    int rr = idx >> 3, cc = (idx & 7) * 8;
    *(u16x8*)&Qs[rr][cc] = *(const u16x8*)&Qp[(qt * 64 + rr) * DKK + cc];
  }
  f32x4 o[4] = {};
  float mrun[4], lrun[4];
  for (int rr = 0; rr < 4; ++rr) { mrun[rr] = -1e30f; lrun[rr] = 0.f; }

  for (int jt = 0; jt <= qt; ++jt) {
    int j0 = jt * 64;
    __syncthreads();  // previous iter's reads of Ks/Vs done (also covers Qs store on iter 0)
    for (int j = 0; j < 2; ++j) {
      int idx = tid + j * 256;
      int rr = idx >> 3, cc = (idx & 7) * 8;
      *(u16x8*)&Ks[rr][cc] = *(const u16x8*)&Kp[(j0 + rr) * DKK + cc];
      *(u16x8*)&Vs[rr][cc] = *(const u16x8*)&Vp[(size_t)rr * SQ + j0 + cc];
    }
    __syncthreads();
    // scores: 16 q x 64 kv per wave
    f32x4 sc[4];
    bf16x8 a0 = *(const bf16x8*)&Qs[w * 16 + lr][lg * 8];
    bf16x8 a1 = *(const bf16x8*)&Qs[w * 16 + lr][32 + lg * 8];
    for (int c = 0; c < 4; ++c) {
      bf16x8 b0 = *(const bf16x8*)&Ks[c * 16 + lr][lg * 8];
      bf16x8 b1 = *(const bf16x8*)&Ks[c * 16 + lr][32 + lg * 8];
      f32x4 z = {};
      z = __builtin_amdgcn_mfma_f32_16x16x32_bf16(a0, b0, z, 0, 0, 0);
      z = __builtin_amdgcn_mfma_f32_16x16x32_bf16(a1, b1, z, 0, 0, 0);
      sc[c] = z;
    }
    int qrow = qt * 64 + w * 16 + lg * 4;
    bool diag = (jt == qt);
    float p[4][4], pm[4];
    for (int rr = 0; rr < 4; ++rr) pm[rr] = -1e30f;
    for (int c = 0; c < 4; ++c) {
      int kv = j0 + c * 16 + lr;
      for (int rr = 0; rr < 4; ++rr) {
        float s = sc[c][rr] * 0.125f;          // 1/sqrt(64)
        if (diag && kv > qrow + rr) s = -1e30f;
        p[c][rr] = s;
        pm[rr] = fmaxf(pm[rr], s);
      }
    }
    for (int off = 1; off < 16; off <<= 1)
      for (int rr = 0; rr < 4; ++rr)
        pm[rr] = fmaxf(pm[rr], __shfl_xor(pm[rr], off, 64));
    float alpha[4], psum[4];
    for (int rr = 0; rr < 4; ++rr) {
      float mnew = fmaxf(mrun[rr], pm[rr]);
      alpha[rr] = __expf(mrun[rr] - mnew);
      mrun[rr] = mnew;
      float su = 0.f;
      for (int c = 0; c < 4; ++c) {
        float e = __expf(p[c][rr] - mnew);
        p[c][rr] = e;
        su += e;
      }
      psum[rr] = su;
    }
    for (int off = 1; off < 16; off <<= 1)
      for (int rr = 0; rr < 4; ++rr)
        psum[rr] += __shfl_xor(psum[rr], off, 64);
    for (int rr = 0; rr < 4; ++rr)
      lrun[rr] = lrun[rr] * alpha[rr] + psum[rr];
    for (int n = 0; n < 4; ++n)
      for (int rr = 0; rr < 4; ++rr)
        o[n][rr] *= alpha[rr];
    // P -> LDS (per-wave region), then barrier so cross-lane reads are safe
    for (int c = 0; c < 4; ++c)
      for (int rr = 0; rr < 4; ++rr)
        Ps[w][lg * 4 + rr][c * 16 + lr] = f2bf(p[c][rr]);
    __syncthreads();
    // PV: O[16 q x 64 dk] += P[16 x 64] * V[64 x 64]
    for (int n = 0; n < 4; ++n)
      for (int kc = 0; kc < 2; ++kc) {
        bf16x8 pa = *(const bf16x8*)&Ps[w][lr][kc * 32 + lg * 8];
        bf16x8 vb = *(const bf16x8*)&Vs[n * 16 + lr][kc * 32 + lg * 8];
        o[n] = __builtin_amdgcn_mfma_f32_16x16x32_bf16(pa, vb, o[n], 0, 0, 0);
      }
  }
  int b = bh >> 4, h = bh & 15;
  int srow = qt * 64 + w * 16 + lg * 4;
  for (int n = 0; n < 4; ++n)
    for (int rr = 0; rr < 4; ++rr) {
      float val = o[n][rr] / lrun[rr];
      Cc[((size_t)(b * SQ + srow + rr)) * DD + h * DKK + n * 16 + lr] = f2bf(val);
    }
}

extern "C" void kernel_launch(void* const* d_in, const int* in_sizes, int n_in,
                              void* d_out, int out_size, void* d_ws, size_t ws_size,
                              hipStream_t stream) {
  (void)in_sizes; (void)n_in; (void)out_size; (void)ws_size;
  const float* x  = (const float*)d_in[0];
  const float* Wq = (const float*)d_in[1];
  const float* Wk = (const float*)d_in[2];
  const float* Wv = (const float*)d_in[3];
  const float* Wo = (const float*)d_in[4];
  float* out = (float*)d_out;
  u16* ws = (u16*)d_ws;
  u16* WT = ws;                     // 3072*1024      = 3,145,728 elems
  u16* Qb = WT + 3145728;           // 2*16*2048*64   = 4,194,304
  u16* Kb = Qb + 4194304;
  u16* Vb = Kb + 4194304;           // V stored (B,H,dk,S)
  u16* Cc = Vb + 4194304;           // concat (B,S,D) = 4,194,304
  // total ws use: ~39.8 MB

  hipLaunchKernelGGL(wt_kernel, dim3(768), dim3(256), 0, stream, Wq, Wk, Wv, WT);
  hipLaunchKernelGGL(gemm_qkv, dim3(64, 48), dim3(256), 0, stream, x, WT, Qb, Kb, Vb);
  hipLaunchKernelGGL(attn_kernel, dim3(32, 32), dim3(256), 0, stream, Qb, Kb, Vb, Cc);
  hipLaunchKernelGGL(gemm_out, dim3(64, 16), dim3(256), 0, stream, Cc, Wo, out);
}

// Round 4
// 169.570 us; speedup vs baseline: 1.3621x; 1.3621x over previous
//
#include <hip/hip_runtime.h>

typedef unsigned short u16;
typedef unsigned int u32;
typedef __bf16 bf16x8 __attribute__((ext_vector_type(8)));
typedef float f32x4 __attribute__((ext_vector_type(4)));
typedef u16 u16x8 __attribute__((ext_vector_type(8)));
typedef u16 u16x4 __attribute__((ext_vector_type(4)));

#define NH 16
#define DKK 64
#define SQ 2048
#define DD 1024

__device__ inline u16 f2bf(float f) {
  union { float f; u32 u; } v; v.f = f;
  u32 u = v.u;
  u += 0x7FFFu + ((u >> 16) & 1u);
  return (u16)(u >> 16);
}

__device__ inline u16x8 cvt8(const float* p) {
  float4 a = *(const float4*)p;
  float4 b = *(const float4*)(p + 4);
  u16x8 v;
  v[0] = f2bf(a.x); v[1] = f2bf(a.y); v[2] = f2bf(a.z); v[3] = f2bf(a.w);
  v[4] = f2bf(b.x); v[5] = f2bf(b.y); v[6] = f2bf(b.z); v[7] = f2bf(b.w);
  return v;
}

// ---------------- Weight transpose: W(H,D,dk) f32 x3 -> WT bf16 [(t*1024 + h*64 + kk)][d] ----------------
__global__ __launch_bounds__(256) void wt_kernel(const float* __restrict__ Wq,
                                                 const float* __restrict__ Wk,
                                                 const float* __restrict__ Wv,
                                                 u16* __restrict__ WT) {
  __shared__ u16 sm[64][72];
  int bid = blockIdx.x;
  int t = bid >> 8;
  int rem = bid & 255;
  int h = rem >> 4;
  int d0 = (rem & 15) * 64;
  const float* src = (t == 0) ? Wq : (t == 1) ? Wk : Wv;
  int tid = threadIdx.x;
  for (int j = 0; j < 2; ++j) {
    int idx = tid + j * 256;
    int r = idx >> 3;
    int c0 = (idx & 7) * 8;
    *(u16x8*)&sm[r][c0] = cvt8(&src[(h * DD + d0 + r) * DKK + c0]);
  }
  __syncthreads();
  for (int j = 0; j < 2; ++j) {
    int idx = tid + j * 256;
    int r2 = idx >> 3;
    int c0 = (idx & 7) * 8;
    u16x8 vv;
    for (int i = 0; i < 8; ++i) vv[i] = sm[c0 + i][r2];
    int n = t * 1024 + h * 64 + r2;
    *(u16x8*)&WT[n * DD + d0 + c0] = vv;
  }
}

// ---------------- QKV GEMM: A=x f32 [M,K]; B=WT bf16 [N,K]; 64x64 tile, 4 waves, BK=32 ----------------
__global__ __launch_bounds__(256) void gemm_qkv(const float* __restrict__ A,
                                                const u16* __restrict__ Bm,
                                                u16* __restrict__ o0,
                                                u16* __restrict__ o1,
                                                u16* __restrict__ o2) {
  __shared__ u16 As[64][40];
  __shared__ u16 Bs[64][40];
  const int K = 1024;
  int m0 = blockIdx.x * 64;
  int n0 = blockIdx.y * 64;
  int tid = threadIdx.x;
  int w = tid >> 6, l = tid & 63;
  int lg = l >> 4, lr = l & 15;
  f32x4 acc[4] = {};
  int r = tid >> 2;
  int c0 = (tid & 3) * 8;
  for (int kt = 0; kt < K / 32; ++kt) {
    int k0 = kt * 32;
    *(u16x8*)&As[r][c0] = cvt8(&A[(size_t)(m0 + r) * K + k0 + c0]);
    *(u16x8*)&Bs[r][c0] = *(const u16x8*)&Bm[(n0 + r) * K + k0 + c0];
    __syncthreads();
    bf16x8 a = *(const bf16x8*)&As[w * 16 + lr][lg * 8];
    for (int j = 0; j < 4; ++j) {
      bf16x8 b = *(const bf16x8*)&Bs[j * 16 + lr][lg * 8];
      acc[j] = __builtin_amdgcn_mfma_f32_16x16x32_bf16(a, b, acc[j], 0, 0, 0);
    }
    __syncthreads();
  }
  int mrow = m0 + w * 16 + lg * 4;
  int t = n0 >> 10;
  int h = (n0 & 1023) >> 6;
  int b = mrow >> 11;
  int s = mrow & 2047;
  for (int j = 0; j < 4; ++j) {
    int kk = j * 16 + lr;
    if (t < 2) {
      u16* o = (t == 0) ? o0 : o1;
      for (int rr = 0; rr < 4; ++rr)
        o[((size_t)(b * NH + h) * SQ + s + rr) * DKK + kk] = f2bf(acc[j][rr]);
    } else {
      u16x4 vv;
      for (int rr = 0; rr < 4; ++rr) vv[rr] = f2bf(acc[j][rr]);
      *(u16x4*)&o2[((size_t)(b * NH + h) * DKK + kk) * SQ + s] = vv;
    }
  }
}

// ---------------- Output GEMM: A=Cc bf16 [M,K]; B=Wo f32 [N,K]; store f32 ----------------
__global__ __launch_bounds__(256) void gemm_out(const u16* __restrict__ A,
                                               const float* __restrict__ Bm,
                                               float* __restrict__ out) {
  __shared__ u16 As[64][40];
  __shared__ u16 Bs[64][40];
  const int K = 1024;
  int m0 = blockIdx.x * 64;
  int n0 = blockIdx.y * 64;
  int tid = threadIdx.x;
  int w = tid >> 6, l = tid & 63;
  int lg = l >> 4, lr = l & 15;
  f32x4 acc[4] = {};
  int r = tid >> 2;
  int c0 = (tid & 3) * 8;
  for (int kt = 0; kt < K / 32; ++kt) {
    int k0 = kt * 32;
    *(u16x8*)&As[r][c0] = *(const u16x8*)&A[(size_t)(m0 + r) * K + k0 + c0];
    *(u16x8*)&Bs[r][c0] = cvt8(&Bm[(size_t)(n0 + r) * K + k0 + c0]);
    __syncthreads();
    bf16x8 a = *(const bf16x8*)&As[w * 16 + lr][lg * 8];
    for (int j = 0; j < 4; ++j) {
      bf16x8 b = *(const bf16x8*)&Bs[j * 16 + lr][lg * 8];
      acc[j] = __builtin_amdgcn_mfma_f32_16x16x32_bf16(a, b, acc[j], 0, 0, 0);
    }
    __syncthreads();
  }
  int mrow = m0 + w * 16 + lg * 4;
  for (int j = 0; j < 4; ++j) {
    int n = n0 + j * 16 + lr;
    for (int rr = 0; rr < 4; ++rr)
      out[(size_t)(mrow + rr) * 1024 + n] = acc[j][rr];
  }
}

// ---------------- Flash attention v2 ----------------
// 4 waves x 16 q rows = 64-q strip per pass; block handles strips {p, 31-p} (33 kv-tiles, balanced).
// Swapped QK^T (mfma(K,Q)) -> per-lane softmax; P via per-wave LDS (b64 stores, no barrier);
// K/V double-buffered, ONE barrier per kv-tile.
__global__ __launch_bounds__(256) void attn_kernel(const u16* __restrict__ Q,
                                                   const u16* __restrict__ Kg,
                                                   const u16* __restrict__ Vt,
                                                   u16* __restrict__ Cc) {
  __shared__ u16 Ks[2][64][72];
  __shared__ u16 Vs[2][64][72];   // [dk][kv]
  __shared__ u16 Ps[4][16][72];   // per-wave P[q][kv]
  int pr = blockIdx.x;
  int bh = blockIdx.y;
  int tid = threadIdx.x;
  int w = tid >> 6, l = tid & 63;
  int lg = l >> 4, lr = l & 15;
  const u16* Qp = Q + (size_t)bh * SQ * DKK;
  const u16* Kp = Kg + (size_t)bh * SQ * DKK;
  const u16* Vp = Vt + (size_t)bh * DKK * SQ;
  int b = bh >> 4, h = bh & 15;
  int strips[2] = { pr, 31 - pr };
  int r0 = tid >> 3;            // 0..31 staging row
  int c0 = (tid & 7) * 8;       // 0..56
  int cur = 0;

  // prologue: stage (strip0, tile0) into buf 0
  {
    #pragma unroll
    for (int it = 0; it < 2; ++it) {
      int rr = r0 + it * 32;
      *(u16x8*)&Ks[0][rr][c0] = *(const u16x8*)&Kp[(size_t)rr * DKK + c0];
      *(u16x8*)&Vs[0][rr][c0] = *(const u16x8*)&Vp[(size_t)rr * SQ + c0];
    }
  }
  __syncthreads();

  for (int si = 0; si < 2; ++si) {
    int s = strips[si];
    int qrow = s * 64 + w * 16 + lr;      // softmax-domain q row for this lane
    bf16x8 qf0 = *(const bf16x8*)&Qp[(size_t)qrow * DKK + lg * 8];
    bf16x8 qf1 = *(const bf16x8*)&Qp[(size_t)qrow * DKK + 32 + lg * 8];
    f32x4 o[4] = {};
    float mrun = -1e30f, lrun = 0.f;

    for (int jt = 0; jt <= s; ++jt) {
      // prefetch next tile in the block's global sequence into buf^1
      int nj = (jt < s) ? (jt + 1) : ((si == 0) ? 0 : -1);
      if (nj >= 0) {
        int j0n = nj * 64;
        #pragma unroll
        for (int it = 0; it < 2; ++it) {
          int rr = r0 + it * 32;
          *(u16x8*)&Ks[cur ^ 1][rr][c0] = *(const u16x8*)&Kp[(size_t)(j0n + rr) * DKK + c0];
          *(u16x8*)&Vs[cur ^ 1][rr][c0] = *(const u16x8*)&Vp[(size_t)rr * SQ + j0n + c0];
        }
      }
      int j0 = jt * 64;
      // QK^T swapped: lane holds S^T col q=qrow, rows kv = j0 + c*16 + lg*4 + rr
      float p[16];
      #pragma unroll
      for (int c = 0; c < 4; ++c) {
        bf16x8 k0 = *(const bf16x8*)&Ks[cur][c * 16 + lr][lg * 8];
        bf16x8 k1 = *(const bf16x8*)&Ks[cur][c * 16 + lr][32 + lg * 8];
        f32x4 z = {};
        z = __builtin_amdgcn_mfma_f32_16x16x32_bf16(k0, qf0, z, 0, 0, 0);
        z = __builtin_amdgcn_mfma_f32_16x16x32_bf16(k1, qf1, z, 0, 0, 0);
        #pragma unroll
        for (int rr = 0; rr < 4; ++rr)
          p[c * 4 + rr] = z[rr] * 0.180336907f;   // (1/8) * log2(e): exp2-domain
      }
      if (jt == s) {  // diagonal tile: causal mask
        #pragma unroll
        for (int c = 0; c < 4; ++c)
          #pragma unroll
          for (int rr = 0; rr < 4; ++rr) {
            int kv = j0 + c * 16 + lg * 4 + rr;
            if (kv > qrow) p[c * 4 + rr] = -1e30f;
          }
      }
      float pm = -1e30f;
      #pragma unroll
      for (int i = 0; i < 16; ++i) pm = fmaxf(pm, p[i]);
      pm = fmaxf(pm, __shfl_xor(pm, 16, 64));
      pm = fmaxf(pm, __shfl_xor(pm, 32, 64));
      float mnew = fmaxf(mrun, pm);
      float alpha = exp2f(mrun - mnew);
      mrun = mnew;
      float su = 0.f;
      #pragma unroll
      for (int i = 0; i < 16; ++i) { p[i] = exp2f(p[i] - mnew); su += p[i]; }
      su += __shfl_xor(su, 16, 64);
      su += __shfl_xor(su, 32, 64);
      lrun = lrun * alpha + su;
      // P[q][kv] per wave: lane's 4 rr-values are kv-consecutive -> b64 store
      #pragma unroll
      for (int c = 0; c < 4; ++c) {
        u16x4 pk;
        #pragma unroll
        for (int rr = 0; rr < 4; ++rr) pk[rr] = f2bf(p[c * 4 + rr]);
        *(u16x4*)&Ps[w][lr][c * 16 + lg * 4] = pk;
      }
      // rescale O (o rows live at q_local = lg*4+rr; alpha lives at lane lr=q_local)
      float af[4];
      #pragma unroll
      for (int rr = 0; rr < 4; ++rr) af[rr] = __shfl(alpha, ((l >> 4) << 2) + rr, 64);
      #pragma unroll
      for (int n = 0; n < 4; ++n)
        #pragma unroll
        for (int rr = 0; rr < 4; ++rr) o[n][rr] *= af[rr];
      // PV: O[16q x 64d] += P[16 x 64] * V^T
      #pragma unroll
      for (int kc = 0; kc < 2; ++kc) {
        bf16x8 pa = *(const bf16x8*)&Ps[w][lr][kc * 32 + lg * 8];
        #pragma unroll
        for (int n = 0; n < 4; ++n) {
          bf16x8 vb = *(const bf16x8*)&Vs[cur][n * 16 + lr][kc * 32 + lg * 8];
          o[n] = __builtin_amdgcn_mfma_f32_16x16x32_bf16(pa, vb, o[n], 0, 0, 0);
        }
      }
      __syncthreads();   // single barrier: drains prefetch, protects buf swap
      cur ^= 1;
    }
    // strip epilogue
    float lrow[4];
    #pragma unroll
    for (int rr = 0; rr < 4; ++rr) lrow[rr] = __shfl(lrun, ((l >> 4) << 2) + rr, 64);
    int srow = s * 64 + w * 16 + lg * 4;
    #pragma unroll
    for (int n = 0; n < 4; ++n)
      #pragma unroll
      for (int rr = 0; rr < 4; ++rr) {
        float val = o[n][rr] / lrow[rr];
        Cc[((size_t)(b * SQ + srow + rr)) * DD + h * DKK + n * 16 + lr] = f2bf(val);
      }
  }
}

extern "C" void kernel_launch(void* const* d_in, const int* in_sizes, int n_in,
                              void* d_out, int out_size, void* d_ws, size_t ws_size,
                              hipStream_t stream) {
  (void)in_sizes; (void)n_in; (void)out_size; (void)ws_size;
  const float* x  = (const float*)d_in[0];
  const float* Wq = (const float*)d_in[1];
  const float* Wk = (const float*)d_in[2];
  const float* Wv = (const float*)d_in[3];
  const float* Wo = (const float*)d_in[4];
  float* out = (float*)d_out;
  u16* ws = (u16*)d_ws;
  u16* WT = ws;                     // 3072*1024
  u16* Qb = WT + 3145728;           // 2*16*2048*64
  u16* Kb = Qb + 4194304;
  u16* Vb = Kb + 4194304;           // V stored (B,H,dk,S)
  u16* Cc = Vb + 4194304;           // concat (B,S,D)

  hipLaunchKernelGGL(wt_kernel, dim3(768), dim3(256), 0, stream, Wq, Wk, Wv, WT);
  hipLaunchKernelGGL(gemm_qkv, dim3(64, 48), dim3(256), 0, stream, x, WT, Qb, Kb, Vb);
  hipLaunchKernelGGL(attn_kernel, dim3(16, 32), dim3(256), 0, stream, Qb, Kb, Vb, Cc);
  hipLaunchKernelGGL(gemm_out, dim3(64, 16), dim3(256), 0, stream, Cc, Wo, out);
}

// Round 5
// 153.099 us; speedup vs baseline: 1.5086x; 1.1076x over previous
//
#include <hip/hip_runtime.h>

typedef unsigned short u16;
typedef unsigned int u32;
typedef __bf16 bf16x8 __attribute__((ext_vector_type(8)));
typedef float f32x4 __attribute__((ext_vector_type(4)));
typedef u16 u16x8 __attribute__((ext_vector_type(8)));
typedef u16 u16x4 __attribute__((ext_vector_type(4)));

#define NH 16
#define DKK 64
#define SQ 2048
#define DD 1024

#define AS1 __attribute__((address_space(1)))
#define AS3 __attribute__((address_space(3)))

__device__ inline u16 f2bf(float f) {
  union { float f; u32 u; } v; v.f = f;
  u32 u = v.u;
  u += 0x7FFFu + ((u >> 16) & 1u);
  return (u16)(u >> 16);
}

__device__ inline u16x8 cvt8(const float* p) {
  float4 a = *(const float4*)p;
  float4 b = *(const float4*)(p + 4);
  u16x8 v;
  v[0] = f2bf(a.x); v[1] = f2bf(a.y); v[2] = f2bf(a.z); v[3] = f2bf(a.w);
  v[4] = f2bf(b.x); v[5] = f2bf(b.y); v[6] = f2bf(b.z); v[7] = f2bf(b.w);
  return v;
}

// direct global->LDS async copy, 16B/lane; LDS dest = wave-uniform base + lane*16
__device__ __forceinline__ void gload16(const u16* g, u16* l) {
  __builtin_amdgcn_global_load_lds((const AS1 u32*)(const void*)g,
                                   (AS3 u32*)(void*)l, 16, 0, 0);
}

// ---------------- f32 -> bf16 bulk convert: x (4M elems) then Wo (1M elems) ----------------
__global__ __launch_bounds__(256) void cvt_kernel(const float* __restrict__ x,
                                                  u16* __restrict__ xb,
                                                  const float* __restrict__ Wo,
                                                  u16* __restrict__ Wob) {
  int bid = blockIdx.x;
  const float* src; u16* dst; size_t base;
  if (bid < 2048) { src = x;  dst = xb;  base = (size_t)bid * 2048; }
  else            { src = Wo; dst = Wob; base = (size_t)(bid - 2048) * 2048; }
  size_t off = base + (size_t)threadIdx.x * 8;
  *(u16x8*)&dst[off] = cvt8(&src[off]);
}

// ---------------- Weight transpose: W(H,D,dk) f32 x3 -> WT bf16 [(t*1024 + h*64 + kk)][d] ----------------
__global__ __launch_bounds__(256) void wt_kernel(const float* __restrict__ Wq,
                                                 const float* __restrict__ Wk,
                                                 const float* __restrict__ Wv,
                                                 u16* __restrict__ WT) {
  __shared__ u16 sm[64][72];
  int bid = blockIdx.x;
  int t = bid >> 8;
  int rem = bid & 255;
  int h = rem >> 4;
  int d0 = (rem & 15) * 64;
  const float* src = (t == 0) ? Wq : (t == 1) ? Wk : Wv;
  int tid = threadIdx.x;
  for (int j = 0; j < 2; ++j) {
    int idx = tid + j * 256;
    int r = idx >> 3;
    int c0 = (idx & 7) * 8;
    *(u16x8*)&sm[r][c0] = cvt8(&src[(h * DD + d0 + r) * DKK + c0]);
  }
  __syncthreads();
  for (int j = 0; j < 2; ++j) {
    int idx = tid + j * 256;
    int r2 = idx >> 3;
    int c0 = (idx & 7) * 8;
    u16x8 vv;
    for (int i = 0; i < 8; ++i) vv[i] = sm[c0 + i][r2];
    int n = t * 1024 + h * 64 + r2;
    *(u16x8*)&WT[n * DD + d0 + c0] = vv;
  }
}

// ---------------- 128x128-tile bf16 GEMM (m97 structure): C = A[M,K] * B[N,K]^T ----------------
// 4 waves (2x2), acc 4x4 frags/wave, BK=32, global_load_lds staging, 2 barriers/K-step.
// mode 0: QKV epilogue (Q,K row-major (B,H,S,dk); V transposed (B,H,dk,S))
// mode 1: f32 store to of[M,1024]
__global__ __launch_bounds__(256) void gemm128(const u16* __restrict__ A,
                                               const u16* __restrict__ Bm,
                                               int mode,
                                               u16* __restrict__ o0,
                                               u16* __restrict__ o1,
                                               u16* __restrict__ o2,
                                               float* __restrict__ of) {
  __shared__ u16 As[128 * 32];
  __shared__ u16 Bs[128 * 32];
  const int K = 1024;
  int m0 = blockIdx.x * 128;
  int n0 = blockIdx.y * 128;
  int tid = threadIdx.x;
  int w = tid >> 6, l = tid & 63;
  int lg = l >> 4, lr = l & 15;
  int wr = w >> 1, wc = w & 1;

  // staging map: round r in {0,1}: lane covers LDS bytes (w*2048 + r*1024 + l*16)
  // -> element row = w*32 + r*16 + (l>>2), col = (l&3)*8
  int srow = w * 32 + (l >> 2);
  int scol = (l & 3) * 8;
  const u16* gA = A + (size_t)(m0 + srow) * K + scol;
  const u16* gB = Bm + (size_t)(n0 + srow) * K + scol;
  u16* lA = As + w * 1024;
  u16* lB = Bs + w * 1024;

  f32x4 acc[4][4] = {};
  for (int kt = 0; kt < 32; ++kt) {
    int k0 = kt * 32;
    gload16(gA + k0, lA);
    gload16(gA + k0 + 16 * K, lA + 512);
    gload16(gB + k0, lB);
    gload16(gB + k0 + 16 * K, lB + 512);
    __syncthreads();   // drains vmcnt (global_load_lds) + cross-wave visibility
    bf16x8 a[4], b[4];
    #pragma unroll
    for (int m = 0; m < 4; ++m)
      a[m] = *(const bf16x8*)&As[(wr * 64 + m * 16 + lr) * 32 + lg * 8];
    #pragma unroll
    for (int n = 0; n < 4; ++n)
      b[n] = *(const bf16x8*)&Bs[(wc * 64 + n * 16 + lr) * 32 + lg * 8];
    #pragma unroll
    for (int m = 0; m < 4; ++m)
      #pragma unroll
      for (int n = 0; n < 4; ++n)
        acc[m][n] = __builtin_amdgcn_mfma_f32_16x16x32_bf16(a[m], b[n], acc[m][n], 0, 0, 0);
    __syncthreads();   // protect LDS overwrite next iter
  }

  if (mode == 1) {
    int mbase = m0 + wr * 64 + lg * 4;
    int nbase = n0 + wc * 64 + lr;
    #pragma unroll
    for (int m = 0; m < 4; ++m)
      #pragma unroll
      for (int n = 0; n < 4; ++n)
        #pragma unroll
        for (int rr = 0; rr < 4; ++rr)
          of[(size_t)(mbase + m * 16 + rr) * 1024 + nbase + n * 16] = acc[m][n][rr];
  } else {
    int t = n0 >> 10;                       // uniform per block (1024 % 128 == 0)
    int h = (((n0 & 1023) + wc * 64) >> 6); // uniform per wave
    int bq = m0 >> 11;                      // uniform (2048 % 128 == 0)
    int sbase = (m0 & 2047) + wr * 64 + lg * 4;
    if (t < 2) {
      u16* o = (t == 0) ? o0 : o1;
      u16* op = o + (size_t)(bq * NH + h) * SQ * DKK;
      #pragma unroll
      for (int m = 0; m < 4; ++m)
        #pragma unroll
        for (int n = 0; n < 4; ++n)
          #pragma unroll
          for (int rr = 0; rr < 4; ++rr)
            op[(size_t)(sbase + m * 16 + rr) * DKK + n * 16 + lr] = f2bf(acc[m][n][rr]);
    } else {
      u16* op = o2 + (size_t)(bq * NH + h) * DKK * SQ;
      #pragma unroll
      for (int m = 0; m < 4; ++m)
        #pragma unroll
        for (int n = 0; n < 4; ++n) {
          u16x4 vv;
          #pragma unroll
          for (int rr = 0; rr < 4; ++rr) vv[rr] = f2bf(acc[m][n][rr]);
          *(u16x4*)&op[(size_t)(n * 16 + lr) * SQ + sbase + m * 16] = vv;
        }
    }
  }
}

// ---------------- Flash attention (round-4 version, unchanged) ----------------
__global__ __launch_bounds__(256) void attn_kernel(const u16* __restrict__ Q,
                                                   const u16* __restrict__ Kg,
                                                   const u16* __restrict__ Vt,
                                                   u16* __restrict__ Cc) {
  __shared__ u16 Ks[2][64][72];
  __shared__ u16 Vs[2][64][72];   // [dk][kv]
  __shared__ u16 Ps[4][16][72];   // per-wave P[q][kv]
  int pr = blockIdx.x;
  int bh = blockIdx.y;
  int tid = threadIdx.x;
  int w = tid >> 6, l = tid & 63;
  int lg = l >> 4, lr = l & 15;
  const u16* Qp = Q + (size_t)bh * SQ * DKK;
  const u16* Kp = Kg + (size_t)bh * SQ * DKK;
  const u16* Vp = Vt + (size_t)bh * DKK * SQ;
  int b = bh >> 4, h = bh & 15;
  int strips[2] = { pr, 31 - pr };
  int r0 = tid >> 3;
  int c0 = (tid & 7) * 8;
  int cur = 0;

  {
    #pragma unroll
    for (int it = 0; it < 2; ++it) {
      int rr = r0 + it * 32;
      *(u16x8*)&Ks[0][rr][c0] = *(const u16x8*)&Kp[(size_t)rr * DKK + c0];
      *(u16x8*)&Vs[0][rr][c0] = *(const u16x8*)&Vp[(size_t)rr * SQ + c0];
    }
  }
  __syncthreads();

  for (int si = 0; si < 2; ++si) {
    int s = strips[si];
    int qrow = s * 64 + w * 16 + lr;
    bf16x8 qf0 = *(const bf16x8*)&Qp[(size_t)qrow * DKK + lg * 8];
    bf16x8 qf1 = *(const bf16x8*)&Qp[(size_t)qrow * DKK + 32 + lg * 8];
    f32x4 o[4] = {};
    float mrun = -1e30f, lrun = 0.f;

    for (int jt = 0; jt <= s; ++jt) {
      int nj = (jt < s) ? (jt + 1) : ((si == 0) ? 0 : -1);
      if (nj >= 0) {
        int j0n = nj * 64;
        #pragma unroll
        for (int it = 0; it < 2; ++it) {
          int rr = r0 + it * 32;
          *(u16x8*)&Ks[cur ^ 1][rr][c0] = *(const u16x8*)&Kp[(size_t)(j0n + rr) * DKK + c0];
          *(u16x8*)&Vs[cur ^ 1][rr][c0] = *(const u16x8*)&Vp[(size_t)rr * SQ + j0n + c0];
        }
      }
      int j0 = jt * 64;
      float p[16];
      #pragma unroll
      for (int c = 0; c < 4; ++c) {
        bf16x8 k0 = *(const bf16x8*)&Ks[cur][c * 16 + lr][lg * 8];
        bf16x8 k1 = *(const bf16x8*)&Ks[cur][c * 16 + lr][32 + lg * 8];
        f32x4 z = {};
        z = __builtin_amdgcn_mfma_f32_16x16x32_bf16(k0, qf0, z, 0, 0, 0);
        z = __builtin_amdgcn_mfma_f32_16x16x32_bf16(k1, qf1, z, 0, 0, 0);
        #pragma unroll
        for (int rr = 0; rr < 4; ++rr)
          p[c * 4 + rr] = z[rr] * 0.180336907f;   // (1/8) * log2(e)
      }
      if (jt == s) {
        #pragma unroll
        for (int c = 0; c < 4; ++c)
          #pragma unroll
          for (int rr = 0; rr < 4; ++rr) {
            int kv = j0 + c * 16 + lg * 4 + rr;
            if (kv > qrow) p[c * 4 + rr] = -1e30f;
          }
      }
      float pm = -1e30f;
      #pragma unroll
      for (int i = 0; i < 16; ++i) pm = fmaxf(pm, p[i]);
      pm = fmaxf(pm, __shfl_xor(pm, 16, 64));
      pm = fmaxf(pm, __shfl_xor(pm, 32, 64));
      float mnew = fmaxf(mrun, pm);
      float alpha = exp2f(mrun - mnew);
      mrun = mnew;
      float su = 0.f;
      #pragma unroll
      for (int i = 0; i < 16; ++i) { p[i] = exp2f(p[i] - mnew); su += p[i]; }
      su += __shfl_xor(su, 16, 64);
      su += __shfl_xor(su, 32, 64);
      lrun = lrun * alpha + su;
      #pragma unroll
      for (int c = 0; c < 4; ++c) {
        u16x4 pk;
        #pragma unroll
        for (int rr = 0; rr < 4; ++rr) pk[rr] = f2bf(p[c * 4 + rr]);
        *(u16x4*)&Ps[w][lr][c * 16 + lg * 4] = pk;
      }
      float af[4];
      #pragma unroll
      for (int rr = 0; rr < 4; ++rr) af[rr] = __shfl(alpha, ((l >> 4) << 2) + rr, 64);
      #pragma unroll
      for (int n = 0; n < 4; ++n)
        #pragma unroll
        for (int rr = 0; rr < 4; ++rr) o[n][rr] *= af[rr];
      #pragma unroll
      for (int kc = 0; kc < 2; ++kc) {
        bf16x8 pa = *(const bf16x8*)&Ps[w][lr][kc * 32 + lg * 8];
        #pragma unroll
        for (int n = 0; n < 4; ++n) {
          bf16x8 vb = *(const bf16x8*)&Vs[cur][n * 16 + lr][kc * 32 + lg * 8];
          o[n] = __builtin_amdgcn_mfma_f32_16x16x32_bf16(pa, vb, o[n], 0, 0, 0);
        }
      }
      __syncthreads();
      cur ^= 1;
    }
    float lrow[4];
    #pragma unroll
    for (int rr = 0; rr < 4; ++rr) lrow[rr] = __shfl(lrun, ((l >> 4) << 2) + rr, 64);
    int srow = s * 64 + w * 16 + lg * 4;
    #pragma unroll
    for (int n = 0; n < 4; ++n)
      #pragma unroll
      for (int rr = 0; rr < 4; ++rr) {
        float val = o[n][rr] / lrow[rr];
        Cc[((size_t)(b * SQ + srow + rr)) * DD + h * DKK + n * 16 + lr] = f2bf(val);
      }
  }
}

extern "C" void kernel_launch(void* const* d_in, const int* in_sizes, int n_in,
                              void* d_out, int out_size, void* d_ws, size_t ws_size,
                              hipStream_t stream) {
  (void)in_sizes; (void)n_in; (void)out_size; (void)ws_size;
  const float* x  = (const float*)d_in[0];
  const float* Wq = (const float*)d_in[1];
  const float* Wk = (const float*)d_in[2];
  const float* Wv = (const float*)d_in[3];
  const float* Wo = (const float*)d_in[4];
  float* out = (float*)d_out;
  u16* ws = (u16*)d_ws;
  u16* WT  = ws;                    // 3,145,728 elems
  u16* Qb  = WT + 3145728;          // 4,194,304
  u16* Kb  = Qb + 4194304;          // 4,194,304
  u16* Vb  = Kb + 4194304;          // 4,194,304 (B,H,dk,S)
  u16* XC  = Vb + 4194304;          // 4,194,304 — xb (bf16 x), later aliased as Cc
  u16* Wob = XC + 4194304;          // 1,048,576
  // total: 20,971,520 u16 = 41.9 MB

  hipLaunchKernelGGL(cvt_kernel, dim3(2560), dim3(256), 0, stream, x, XC, Wo, Wob);
  hipLaunchKernelGGL(wt_kernel, dim3(768), dim3(256), 0, stream, Wq, Wk, Wv, WT);
  hipLaunchKernelGGL(gemm128, dim3(32, 24), dim3(256), 0, stream, XC, WT, 0, Qb, Kb, Vb, (float*)nullptr);
  hipLaunchKernelGGL(attn_kernel, dim3(16, 32), dim3(256), 0, stream, Qb, Kb, Vb, XC);
  hipLaunchKernelGGL(gemm128, dim3(32, 8), dim3(256), 0, stream, XC, Wob, 1, nullptr, nullptr, nullptr, out);
}

// Round 6
// 147.916 us; speedup vs baseline: 1.5615x; 1.0350x over previous
//
#include <hip/hip_runtime.h>

typedef unsigned short u16;
typedef unsigned int u32;
typedef __bf16 bf16x8 __attribute__((ext_vector_type(8)));
typedef float f32x4 __attribute__((ext_vector_type(4)));
typedef u16 u16x8 __attribute__((ext_vector_type(8)));
typedef u16 u16x4 __attribute__((ext_vector_type(4)));
typedef u32 u32x2 __attribute__((ext_vector_type(2)));

#define NH 16
#define DKK 64
#define SQ 2048
#define DD 1024

#define AS1 __attribute__((address_space(1)))
#define AS3 __attribute__((address_space(3)))

// softmax scale folded with log2(e): (1/8) * 1.44269504
#define QSCALE 0.1803368925f

__device__ inline u16 f2bf(float f) {
  union { float f; u32 u; } v; v.f = f;
  u32 u = v.u;
  u += 0x7FFFu + ((u >> 16) & 1u);
  return (u16)(u >> 16);
}

__device__ __forceinline__ u32 cvtpk(float lo, float hi) {
  u32 r;
  asm("v_cvt_pk_bf16_f32 %0, %1, %2" : "=v"(r) : "v"(lo), "v"(hi));
  return r;
}

__device__ inline u16x8 cvt8(const float* p) {
  float4 a = *(const float4*)p;
  float4 b = *(const float4*)(p + 4);
  u16x8 v;
  v[0] = f2bf(a.x); v[1] = f2bf(a.y); v[2] = f2bf(a.z); v[3] = f2bf(a.w);
  v[4] = f2bf(b.x); v[5] = f2bf(b.y); v[6] = f2bf(b.z); v[7] = f2bf(b.w);
  return v;
}

// direct global->LDS async copy, 16B/lane; LDS dest = wave-uniform base + lane*16
__device__ __forceinline__ void gload16(const u16* g, u16* l) {
  __builtin_amdgcn_global_load_lds((const AS1 u32*)(const void*)g,
                                   (AS3 u32*)(void*)l, 16, 0, 0);
}

// ---------------- f32 -> bf16 bulk convert: x (4M elems) then Wo (1M elems) ----------------
__global__ __launch_bounds__(256) void cvt_kernel(const float* __restrict__ x,
                                                  u16* __restrict__ xb,
                                                  const float* __restrict__ Wo,
                                                  u16* __restrict__ Wob) {
  int bid = blockIdx.x;
  const float* src; u16* dst; size_t base;
  if (bid < 2048) { src = x;  dst = xb;  base = (size_t)bid * 2048; }
  else            { src = Wo; dst = Wob; base = (size_t)(bid - 2048) * 2048; }
  size_t off = base + (size_t)threadIdx.x * 8;
  *(u16x8*)&dst[off] = cvt8(&src[off]);
}

// ---------------- Weight transpose: W(H,D,dk) f32 x3 -> WT bf16 [(t*1024 + h*64 + kk)][d] ----------------
__global__ __launch_bounds__(256) void wt_kernel(const float* __restrict__ Wq,
                                                 const float* __restrict__ Wk,
                                                 const float* __restrict__ Wv,
                                                 u16* __restrict__ WT) {
  __shared__ u16 sm[64][72];
  int bid = blockIdx.x;
  int t = bid >> 8;
  int rem = bid & 255;
  int h = rem >> 4;
  int d0 = (rem & 15) * 64;
  const float* src = (t == 0) ? Wq : (t == 1) ? Wk : Wv;
  int tid = threadIdx.x;
  for (int j = 0; j < 2; ++j) {
    int idx = tid + j * 256;
    int r = idx >> 3;
    int c0 = (idx & 7) * 8;
    *(u16x8*)&sm[r][c0] = cvt8(&src[(h * DD + d0 + r) * DKK + c0]);
  }
  __syncthreads();
  for (int j = 0; j < 2; ++j) {
    int idx = tid + j * 256;
    int r2 = idx >> 3;
    int c0 = (idx & 7) * 8;
    u16x8 vv;
    for (int i = 0; i < 8; ++i) vv[i] = sm[c0 + i][r2];
    int n = t * 1024 + h * 64 + r2;
    *(u16x8*)&WT[n * DD + d0 + c0] = vv;
  }
}

// ---------------- 128x128-tile bf16 GEMM (m97 structure): C = A[M,K] * B[N,K]^T ----------------
// mode 0: QKV epilogue (Q pre-scaled by QSCALE; Q,K row-major (B,H,S,dk); V transposed (B,H,dk,S))
// mode 1: f32 store to of[M,1024]
__global__ __launch_bounds__(256) void gemm128(const u16* __restrict__ A,
                                               const u16* __restrict__ Bm,
                                               int mode,
                                               u16* __restrict__ o0,
                                               u16* __restrict__ o1,
                                               u16* __restrict__ o2,
                                               float* __restrict__ of) {
  __shared__ u16 As[128 * 32];
  __shared__ u16 Bs[128 * 32];
  const int K = 1024;
  int m0 = blockIdx.x * 128;
  int n0 = blockIdx.y * 128;
  int tid = threadIdx.x;
  int w = tid >> 6, l = tid & 63;
  int lg = l >> 4, lr = l & 15;
  int wr = w >> 1, wc = w & 1;

  int srow = w * 32 + (l >> 2);
  int scol = (l & 3) * 8;
  const u16* gA = A + (size_t)(m0 + srow) * K + scol;
  const u16* gB = Bm + (size_t)(n0 + srow) * K + scol;
  u16* lA = As + w * 1024;
  u16* lB = Bs + w * 1024;

  f32x4 acc[4][4] = {};
  for (int kt = 0; kt < 32; ++kt) {
    int k0 = kt * 32;
    gload16(gA + k0, lA);
    gload16(gA + k0 + 16 * K, lA + 512);
    gload16(gB + k0, lB);
    gload16(gB + k0 + 16 * K, lB + 512);
    __syncthreads();
    bf16x8 a[4], b[4];
    #pragma unroll
    for (int m = 0; m < 4; ++m)
      a[m] = *(const bf16x8*)&As[(wr * 64 + m * 16 + lr) * 32 + lg * 8];
    #pragma unroll
    for (int n = 0; n < 4; ++n)
      b[n] = *(const bf16x8*)&Bs[(wc * 64 + n * 16 + lr) * 32 + lg * 8];
    #pragma unroll
    for (int m = 0; m < 4; ++m)
      #pragma unroll
      for (int n = 0; n < 4; ++n)
        acc[m][n] = __builtin_amdgcn_mfma_f32_16x16x32_bf16(a[m], b[n], acc[m][n], 0, 0, 0);
    __syncthreads();
  }

  if (mode == 1) {
    int mbase = m0 + wr * 64 + lg * 4;
    int nbase = n0 + wc * 64 + lr;
    #pragma unroll
    for (int m = 0; m < 4; ++m)
      #pragma unroll
      for (int n = 0; n < 4; ++n)
        #pragma unroll
        for (int rr = 0; rr < 4; ++rr)
          of[(size_t)(mbase + m * 16 + rr) * 1024 + nbase + n * 16] = acc[m][n][rr];
  } else {
    int t = n0 >> 10;
    int h = (((n0 & 1023) + wc * 64) >> 6);
    int bq = m0 >> 11;
    int sbase = (m0 & 2047) + wr * 64 + lg * 4;
    if (t < 2) {
      float sc = (t == 0) ? QSCALE : 1.0f;   // fold softmax scale*log2e into Q
      u16* o = (t == 0) ? o0 : o1;
      u16* op = o + (size_t)(bq * NH + h) * SQ * DKK;
      #pragma unroll
      for (int m = 0; m < 4; ++m)
        #pragma unroll
        for (int n = 0; n < 4; ++n)
          #pragma unroll
          for (int rr = 0; rr < 4; ++rr)
            op[(size_t)(sbase + m * 16 + rr) * DKK + n * 16 + lr] = f2bf(acc[m][n][rr] * sc);
    } else {
      u16* op = o2 + (size_t)(bq * NH + h) * DKK * SQ;
      #pragma unroll
      for (int m = 0; m < 4; ++m)
        #pragma unroll
        for (int n = 0; n < 4; ++n) {
          u16x4 vv;
          #pragma unroll
          for (int rr = 0; rr < 4; ++rr) vv[rr] = f2bf(acc[m][n][rr]);
          *(u16x4*)&op[(size_t)(n * 16 + lr) * SQ + sbase + m * 16] = vv;
        }
    }
  }
}

// ---------------- Flash attention v3 ----------------
// gload_lds K/V staging with XOR-swizzled source (granule ^= row&7), swizzled ds_reads;
// Q pre-scaled; defer-max rescale; cvt_pk P pack. 1 barrier/tile, K/V double-buffered.
__global__ __launch_bounds__(256) void attn_kernel(const u16* __restrict__ Q,
                                                   const u16* __restrict__ Kg,
                                                   const u16* __restrict__ Vt,
                                                   u16* __restrict__ Cc) {
  __shared__ u16 Ks[2][64 * 64];
  __shared__ u16 Vs[2][64 * 64];   // [dk][kv]
  __shared__ u16 Ps[4][16][72];    // per-wave P[q][kv]
  int pr = blockIdx.x;
  int bh = blockIdx.y;
  int tid = threadIdx.x;
  int w = tid >> 6, l = tid & 63;
  int lg = l >> 4, lr = l & 15;
  const u16* Qp = Q + (size_t)bh * SQ * DKK;
  const u16* Kp = Kg + (size_t)bh * SQ * DKK;
  const u16* Vp = Vt + (size_t)bh * DKK * SQ;
  int b = bh >> 4, h = bh & 15;
  int strips[2] = { pr, 31 - pr };
  int cur = 0;

  // staging geometry: per wave, 2 gloads of 1KB; gload 'it' covers rows w*16+it*8 .. +7
  int lrow8 = l >> 3;              // 0..7  (row within the 8-row gload)
  int swz = (l & 7) ^ lrow8;       // swizzled source granule
  int r7 = lr & 7;                 // read-side swizzle key
  // K source element offset (w/o tile base): row*64 + swz*8 ; V: row*SQ + swz*8
  const u16* kSrc0 = Kp + (size_t)(w * 16 + lrow8) * DKK + swz * 8;
  const u16* kSrc1 = Kp + (size_t)(w * 16 + 8 + lrow8) * DKK + swz * 8;
  const u16* vSrc0 = Vp + (size_t)(w * 16 + lrow8) * SQ + swz * 8;
  const u16* vSrc1 = Vp + (size_t)(w * 16 + 8 + lrow8) * SQ + swz * 8;

  #define STAGE(buf, j0)                                                  \
    do {                                                                  \
      gload16(kSrc0 + (size_t)(j0) * DKK, &Ks[buf][(w * 16) * 64]);       \
      gload16(kSrc1 + (size_t)(j0) * DKK, &Ks[buf][(w * 16 + 8) * 64]);   \
      gload16(vSrc0 + (j0), &Vs[buf][(w * 16) * 64]);                     \
      gload16(vSrc1 + (j0), &Vs[buf][(w * 16 + 8) * 64]);                 \
    } while (0)

  STAGE(0, 0);
  __syncthreads();

  for (int si = 0; si < 2; ++si) {
    int s = strips[si];
    int qrow = s * 64 + w * 16 + lr;
    bf16x8 qf0 = *(const bf16x8*)&Qp[(size_t)qrow * DKK + lg * 8];
    bf16x8 qf1 = *(const bf16x8*)&Qp[(size_t)qrow * DKK + 32 + lg * 8];
    f32x4 o[4] = {};
    float mrun = -1e30f, lrun = 0.f;

    for (int jt = 0; jt <= s; ++jt) {
      int nj = (jt < s) ? (jt + 1) : ((si == 0) ? 0 : -1);
      if (nj >= 0) STAGE(cur ^ 1, nj * 64);

      int j0 = jt * 64;
      float p[16];
      #pragma unroll
      for (int c = 0; c < 4; ++c) {
        int R = c * 16 + lr;
        const u16* kr = &Ks[cur][R * 64];
        bf16x8 k0 = *(const bf16x8*)&kr[(lg ^ r7) * 8];
        bf16x8 k1 = *(const bf16x8*)&kr[((4 + lg) ^ r7) * 8];
        f32x4 z = {};
        z = __builtin_amdgcn_mfma_f32_16x16x32_bf16(k0, qf0, z, 0, 0, 0);
        z = __builtin_amdgcn_mfma_f32_16x16x32_bf16(k1, qf1, z, 0, 0, 0);
        #pragma unroll
        for (int rr = 0; rr < 4; ++rr) p[c * 4 + rr] = z[rr];
      }
      if (jt == s) {  // causal mask on diagonal tile
        #pragma unroll
        for (int c = 0; c < 4; ++c)
          #pragma unroll
          for (int rr = 0; rr < 4; ++rr) {
            int kv = j0 + c * 16 + lg * 4 + rr;
            if (kv > qrow) p[c * 4 + rr] = -1e30f;
          }
      }
      float pm = p[0];
      #pragma unroll
      for (int i = 1; i < 16; ++i) pm = fmaxf(pm, p[i]);
      pm = fmaxf(pm, __shfl_xor(pm, 16, 64));
      pm = fmaxf(pm, __shfl_xor(pm, 32, 64));
      float alpha = 1.0f;
      if (__any(pm > mrun + 11.0f)) {        // defer-max: rescale only on real growth
        float mnew = fmaxf(mrun, pm);
        alpha = exp2f(mrun - mnew);
        mrun = mnew;
        float af[4];
        #pragma unroll
        for (int rr = 0; rr < 4; ++rr) af[rr] = __shfl(alpha, ((l >> 4) << 2) + rr, 64);
        #pragma unroll
        for (int n = 0; n < 4; ++n)
          #pragma unroll
          for (int rr = 0; rr < 4; ++rr) o[n][rr] *= af[rr];
      }
      float su = 0.f;
      #pragma unroll
      for (int i = 0; i < 16; ++i) { p[i] = exp2f(p[i] - mrun); su += p[i]; }
      su += __shfl_xor(su, 16, 64);
      su += __shfl_xor(su, 32, 64);
      lrun = lrun * alpha + su;
      #pragma unroll
      for (int c = 0; c < 4; ++c) {
        u32x2 pk2;
        pk2[0] = cvtpk(p[c * 4 + 0], p[c * 4 + 1]);
        pk2[1] = cvtpk(p[c * 4 + 2], p[c * 4 + 3]);
        *(u32x2*)&Ps[w][lr][c * 16 + lg * 4] = pk2;
      }
      // PV: O[16q x 64d] += P[16 x 64] * V^T (Vs swizzle-read)
      #pragma unroll
      for (int kc = 0; kc < 2; ++kc) {
        bf16x8 pa = *(const bf16x8*)&Ps[w][lr][kc * 32 + lg * 8];
        #pragma unroll
        for (int n = 0; n < 4; ++n) {
          int R2 = n * 16 + lr;
          bf16x8 vb = *(const bf16x8*)&Vs[cur][R2 * 64 + (((kc * 4 + lg) ^ r7) * 8)];
          o[n] = __builtin_amdgcn_mfma_f32_16x16x32_bf16(pa, vb, o[n], 0, 0, 0);
        }
      }
      __syncthreads();
      cur ^= 1;
    }
    float lrow[4];
    #pragma unroll
    for (int rr = 0; rr < 4; ++rr) lrow[rr] = __shfl(lrun, ((l >> 4) << 2) + rr, 64);
    int srow = s * 64 + w * 16 + lg * 4;
    #pragma unroll
    for (int n = 0; n < 4; ++n)
      #pragma unroll
      for (int rr = 0; rr < 4; ++rr) {
        float val = o[n][rr] / lrow[rr];
        Cc[((size_t)(b * SQ + srow + rr)) * DD + h * DKK + n * 16 + lr] = f2bf(val);
      }
  }
  #undef STAGE
}

extern "C" void kernel_launch(void* const* d_in, const int* in_sizes, int n_in,
                              void* d_out, int out_size, void* d_ws, size_t ws_size,
                              hipStream_t stream) {
  (void)in_sizes; (void)n_in; (void)out_size; (void)ws_size;
  const float* x  = (const float*)d_in[0];
  const float* Wq = (const float*)d_in[1];
  const float* Wk = (const float*)d_in[2];
  const float* Wv = (const float*)d_in[3];
  const float* Wo = (const float*)d_in[4];
  float* out = (float*)d_out;
  u16* ws = (u16*)d_ws;
  u16* WT  = ws;                    // 3,145,728 elems
  u16* Qb  = WT + 3145728;          // 4,194,304
  u16* Kb  = Qb + 4194304;          // 4,194,304
  u16* Vb  = Kb + 4194304;          // 4,194,304 (B,H,dk,S)
  u16* XC  = Vb + 4194304;          // 4,194,304 — xb (bf16 x), later aliased as Cc
  u16* Wob = XC + 4194304;          // 1,048,576

  hipLaunchKernelGGL(cvt_kernel, dim3(2560), dim3(256), 0, stream, x, XC, Wo, Wob);
  hipLaunchKernelGGL(wt_kernel, dim3(768), dim3(256), 0, stream, Wq, Wk, Wv, WT);
  hipLaunchKernelGGL(gemm128, dim3(32, 24), dim3(256), 0, stream, XC, WT, 0, Qb, Kb, Vb, (float*)nullptr);
  hipLaunchKernelGGL(attn_kernel, dim3(16, 32), dim3(256), 0, stream, Qb, Kb, Vb, XC);
  hipLaunchKernelGGL(gemm128, dim3(32, 8), dim3(256), 0, stream, XC, Wob, 1, nullptr, nullptr, nullptr, out);
}